// Round 9
// baseline (133.682 us; speedup 1.0000x reference)
//
#include <hip/hip_runtime.h>

using v8h  = __attribute__((ext_vector_type(8))) __fp16;
using h2   = __attribute__((ext_vector_type(2))) __fp16;
using v16f = __attribute__((ext_vector_type(16))) float;
using v4f  = __attribute__((ext_vector_type(4))) float;

#define B_SIZE 262144
// ws float offsets
#define WS_S1    8192    // (inside partial slices) S1[k][d]
#define WS_GS    8448    // (inside partial slices) gsum[k]
#define WS_SING  8456    // 8 : per-k singularity partials
#define WS_C1    8464    // 8 : log(phi)-0.5(logdet+Dlog2pi+|lmu|^2)
#define WS_L16   8736    // 4352 floats = 8704 halfs : M' [272 rows][32] f16
#define WS_ENP   13184   // 1024 energy partials
#define WS_RCP   14208   // 1024 recon partials
#define WS_PART  15360   // 512 x 8464 moment partials (17.3 MB)
#define WS_PART2 4349952 // 8 x 8464 stage-1 reduce partials
#define PART_STRIDE 8464
#define MOM_BLK  512     // 512-thread blocks, 512 rows each
#define EN_BLK   1024    // 256-thread blocks

union PkU { h2 p[4]; v8h v; };

__device__ __forceinline__ float lane_bcast(float v, int l) {
  return __builtin_bit_cast(float,
      __builtin_amdgcn_readlane(__builtin_bit_cast(int, v), l));
}

// ---------------------------------------------------------------------------
// Kernel 1: raw moments. 8 waves/block, wave w owns k=w. Barrier-free:
// each wave stages its 16-row feat chunk into a PRIVATE LDS region with
// float4 loads (2 per lane) + ds_write_b128, reads MFMA fragments from it
// (in-wave lgkmcnt ordering), and writes its S2 tile straight to the
// block's partial slice. 32x32x16 layouts: B[kk][n=c], kk=half*8+j;
// C/D: col=lane&31, row=(reg&3)+8*(reg>>2)+4*(lane>>5).
// ---------------------------------------------------------------------------
__global__ __launch_bounds__(512, 4) void k_moments(
    const float* __restrict__ gamma, const float* __restrict__ feat,
    float* __restrict__ part) {
  __shared__ float stg[8][512];                // 16 KB, wave-private chunks
  const int tid = threadIdx.x, lane = tid & 63, k = tid >> 6;  // k = wave id
  const int c = lane & 31, half = lane >> 5;
  const int base = blockIdx.x * 512;

  v16f acc;
#pragma unroll
  for (int r = 0; r < 16; ++r) acc[r] = 0.f;
  float s1a = 0.f, ga = 0.f;

  float* st = &stg[k][0];
#pragma unroll 2
  for (int ch = 0; ch < 32; ++ch) {            // 32 chunks of 16 rows
    const int rb16 = base + ch * 16;
    // stage 16 rows x 32 cols via float4 (perfectly coalesced)
    const float4* src = (const float4*)(feat + (size_t)rb16 * 32);
    const float4 va = src[lane];
    const float4 vb = src[lane + 64];
    ((float4*)st)[lane] = va;
    ((float4*)st)[lane + 64] = vb;

    float g8[8];
#pragma unroll
    for (int j = 0; j < 8; ++j)
      g8[j] = gamma[(size_t)(rb16 + half * 8 + j) * 8 + k];

    float fc[8];
#pragma unroll
    for (int j = 0; j < 8; ++j) fc[j] = st[(half * 8 + j) * 32 + c];

    PkU fp, gp;
#pragma unroll
    for (int jj = 0; jj < 4; ++jj) {
      fp.p[jj] = __builtin_amdgcn_cvt_pkrtz(fc[2 * jj], fc[2 * jj + 1]);
      gp.p[jj] = __builtin_amdgcn_cvt_pkrtz(g8[2 * jj], g8[2 * jj + 1]);
    }
#pragma unroll
    for (int j = 0; j < 8; ++j) {
      s1a = fmaf(g8[j], fc[j], s1a);
      ga += g8[j];
    }
    const v8h af = gp.v * fp.v;                // gamma_k ⊙ f
    acc = __builtin_amdgcn_mfma_f32_32x32x16_f16(af, fp.v, acc, 0, 0, 0);
  }

  // direct global epilogue (no LDS tiles, no barrier)
  float* pb = part + (size_t)blockIdx.x * PART_STRIDE;
#pragma unroll
  for (int r = 0; r < 16; ++r) {
    const int row = (r & 3) + 8 * (r >> 2) + 4 * half;
    pb[k * 1024 + row * 32 + c] = acc[r];
  }
  s1a += __shfl_xor(s1a, 32);                  // combine halves
  ga  += __shfl_xor(ga, 32);
  if (half == 0) pb[WS_S1 + k * 32 + c] = s1a;
  if (lane == 0) pb[WS_GS + k] = ga;
}

// ---------------------------------------------------------------------------
// Kernel 1b: stage-1 partial reduction; block (x,y) sums slices [64y,64y+64).
// ---------------------------------------------------------------------------
__global__ void k_reduce(const float* __restrict__ part, float* __restrict__ p2) {
  const int t = blockIdx.x * 256 + threadIdx.x;
  if (t >= 8456) return;
  const int y = blockIdx.y;
  float s = 0.f;
#pragma unroll 8
  for (int b = y * 64; b < y * 64 + 64; ++b)
    s += part[(size_t)b * PART_STRIDE + t];
  p2[(size_t)y * PART_STRIDE + t] = s;
}

// ---------------------------------------------------------------------------
// Kernel 2: one k per block, single wave. Sums the 8 stage-1 slices itself,
// then in-register Cholesky/solves with readlane broadcasts.
// ---------------------------------------------------------------------------
__global__ __launch_bounds__(64, 1) void k_prepare(
    const float* __restrict__ p2, float* __restrict__ ws) {
  __shared__ float T[32 * 33];
  const int k = blockIdx.x;
  const int i = threadIdx.x & 63;
  const int ri = i & 31;
  const bool act = i < 32;

  // sum 8 stage-1 slices: sigma row, S1 row, gsum
  float a[32];
#pragma unroll
  for (int j = 0; j < 32; ++j) a[j] = 0.f;
  float s1i = 0.f, gs = 0.f;
#pragma unroll
  for (int y = 0; y < 8; ++y) {
    const float* sl = p2 + (size_t)y * PART_STRIDE;
    const float4* s2p = (const float4*)(sl + k * 1024 + ri * 32);
#pragma unroll
    for (int t = 0; t < 8; ++t) {
      const float4 q = s2p[t];
      a[4 * t + 0] += q.x; a[4 * t + 1] += q.y;
      a[4 * t + 2] += q.z; a[4 * t + 3] += q.w;
    }
    s1i += sl[WS_S1 + k * 32 + ri];
    gs  += sl[WS_GS + k];
  }

  const float denom = gs + 1e-8f;
  const float rden = __builtin_amdgcn_rcpf(denom);
  const float mu_i = s1i * rden;

  float sing = 0.f;
#pragma unroll
  for (int j = 0; j < 32; ++j) {
    const float muj = lane_bcast(mu_i, j);
    const float s1j = lane_bcast(s1i, j);
    float sig = a[j] - mu_i * s1j - muj * s1i + gs * mu_i * muj;
    sig = sig * rden + ((ri == j) ? 1e-6f : 0.f);
    a[j] = sig;
    if (ri == j) sing = __builtin_amdgcn_rcpf(sig + 1e-8f);
  }
  if (!act) sing = 0.f;
#pragma unroll
  for (int m = 1; m < 64; m <<= 1) sing += __shfl_xor(sing, m);
  if (i == 0) ws[WS_SING + k] = sing;

  float logdet = 0.f;
#pragma unroll
  for (int j = 0; j < 32; ++j) {
    const float ajj = lane_bcast(a[j], j);
    const float ljj = __builtin_amdgcn_sqrtf(ajj);
    const float rljj = __builtin_amdgcn_rcpf(ljj);
    logdet += __logf(ajj);
    const float lij = (ri == j) ? ljj : ((ri > j) ? a[j] * rljj : 0.f);
    a[j] = lij;
#pragma unroll
    for (int p = j + 1; p < 32; ++p) {
      const float lpj = lane_bcast(lij, p);
      a[p] = fmaf(-lij, lpj, a[p]);
    }
  }

  const int c = ri;
  float x[32];
#pragma unroll
  for (int r = 0; r < 32; ++r) {
    float s = (r == c) ? 1.f : 0.f;
#pragma unroll
    for (int p = 0; p < r; ++p) {
      const float lrp = lane_bcast(a[p], r);
      s = fmaf(-lrp, x[p], s);
    }
    x[r] = s * __builtin_amdgcn_rcpf(lane_bcast(a[r], r));
  }

  if (act) {
#pragma unroll
    for (int r = 0; r < 32; ++r) T[r * 33 + c] = x[r];
  }
  __syncthreads();
  float xr[32];
#pragma unroll
  for (int p = 0; p < 32; ++p) xr[p] = T[ri * 33 + p];

  __fp16* l16 = (__fp16*)(ws + WS_L16);
  if (act) {
#pragma unroll
    for (int t = 0; t < 4; ++t) {
      PkU h4;
#pragma unroll
      for (int u = 0; u < 4; ++u)
        h4.p[u] = __builtin_amdgcn_cvt_pkrtz(xr[8 * t + 2 * u], xr[8 * t + 2 * u + 1]);
      *(v8h*)(l16 + (size_t)(k * 32 + ri) * 32 + 8 * t) = h4.v;
    }
  }

  float lm = 0.f;
#pragma unroll
  for (int p = 0; p < 32; ++p) lm = fmaf(xr[p], lane_bcast(mu_i, p), lm);

  float lm2 = act ? lm * lm : 0.f;
#pragma unroll
  for (int m = 1; m < 64; m <<= 1) lm2 += __shfl_xor(lm2, m);

  float q = 0.f;
#pragma unroll
  for (int j = 0; j < 32; ++j) q = fmaf(x[j], lane_bcast(lm, j), q);
  if (act) {
    l16[(size_t)(256 + k) * 32 + c] = (__fp16)q;
    l16[(size_t)(264 + k) * 32 + c] = (__fp16)0.f;
  }

  if (i == 0) {
    const float phi = gs * (1.f / (float)B_SIZE);
    ws[WS_C1 + k] =
        __logf(phi + 1e-10f) - 0.5f * (logdet + 32.f * logf(6.28318f)) - 0.5f * lm2;
  }
}

// ---------------------------------------------------------------------------
// Kernel 3: Y = M' F^T via 16x16x32 MFMA; w = c1' + f.q_k - 0.5|y|^2.
// ---------------------------------------------------------------------------
__global__ __launch_bounds__(256, 4) void k_energy(
    const float* __restrict__ feat, const float* __restrict__ rec,
    const float* __restrict__ ws, float* __restrict__ aws) {
  __shared__ float ben[4], brc[4];
  const int tid = threadIdx.x, lane = tid & 63, wv = tid >> 6;
  const int gw = blockIdx.x * 4 + wv;
  const int ROWS = B_SIZE / (EN_BLK * 4);      // 64
  const int base = gw * ROWS;
  const int cl = lane & 15, g = lane >> 4;
  const int p0 = g * 8;

  const __fp16* l16 = (const __fp16*)(ws + WS_L16);
  v8h mf[17];
#pragma unroll
  for (int t = 0; t < 17; ++t)
    mf[t] = *(const v8h*)(l16 + (size_t)(16 * t + cl) * 32 + p0);
  float c1[8];
#pragma unroll
  for (int k = 0; k < 8; ++k) c1[k] = ws[WS_C1 + k];

  float en_acc = 0.f, rv_acc = 0.f;
  const v4f zf = {0.f, 0.f, 0.f, 0.f};

  for (int ch = 0; ch < ROWS / 16; ++ch) {
    const int b0 = base + ch * 16;
    const size_t row = (size_t)(b0 + cl) * 32;
    const float4 fa = *(const float4*)(feat + row + p0);
    const float4 fb = *(const float4*)(feat + row + p0 + 4);
    PkU af;
    af.p[0] = __builtin_amdgcn_cvt_pkrtz(fa.x, fa.y);
    af.p[1] = __builtin_amdgcn_cvt_pkrtz(fa.z, fa.w);
    af.p[2] = __builtin_amdgcn_cvt_pkrtz(fb.x, fb.y);
    af.p[3] = __builtin_amdgcn_cvt_pkrtz(fb.z, fb.w);

    float zk[8];
#pragma unroll
    for (int k = 0; k < 8; ++k) zk[k] = 0.f;
    float yq[4];

#pragma unroll
    for (int t = 0; t < 17; ++t) {
      const v4f y = __builtin_amdgcn_mfma_f32_16x16x32_f16(mf[t], af.v, zf, 0, 0, 0);
      if (t < 16) {
#pragma unroll
        for (int r = 0; r < 4; ++r) zk[t >> 1] = fmaf(y[r], y[r], zk[t >> 1]);
      } else {
#pragma unroll
        for (int r = 0; r < 4; ++r) yq[r] = y[r];
      }
    }
#pragma unroll
    for (int m = 16; m < 64; m <<= 1)
#pragma unroll
      for (int k = 0; k < 8; ++k) zk[k] += __shfl_xor(zk[k], m);

    float mx = -3.0e38f, s = 0.f;
#pragma unroll
    for (int k = 0; k < 8; ++k) {
      const float yp = __shfl(yq[k & 3], cl + ((k >> 2) << 4));
      const float w = c1[k] + yp - 0.5f * zk[k];
      const float mn = fmaxf(mx, w);
      s = s * __expf(mx - mn) + __expf(w - mn);
      mx = mn;
    }
    float en = -(mx + __logf(s + 1e-10f));
    en = (en == en && en < 1e38f && en > -1e38f) ? en : 0.f;
    if (lane < 16) {
      en_acc += en;
      rv_acc += rec[b0 + cl];
    }
  }
#pragma unroll
  for (int m = 32; m; m >>= 1) {
    en_acc += __shfl_down(en_acc, m);
    rv_acc += __shfl_down(rv_acc, m);
  }
  if (lane == 0) { ben[wv] = en_acc; brc[wv] = rv_acc; }
  __syncthreads();
  if (tid == 0) {
    aws[WS_ENP + blockIdx.x] = ben[0] + ben[1] + ben[2] + ben[3];
    aws[WS_RCP + blockIdx.x] = brc[0] + brc[1] + brc[2] + brc[3];
  }
}

// ---------------------------------------------------------------------------
// Kernel 4: final reduction + combine.
// ---------------------------------------------------------------------------
__global__ void k_final(const float* __restrict__ ws, float* __restrict__ out) {
  __shared__ float r1[256], r2[256];
  const int tid = threadIdx.x;
  float e = 0.f, r = 0.f;
  for (int i = tid; i < EN_BLK; i += 256) {
    e += ws[WS_ENP + i];
    r += ws[WS_RCP + i];
  }
  r1[tid] = e; r2[tid] = r;
  __syncthreads();
  for (int s = 128; s > 0; s >>= 1) {
    if (tid < s) { r1[tid] += r1[tid + s]; r2[tid] += r2[tid + s]; }
    __syncthreads();
  }
  if (tid == 0) {
    float sing = 0.f;
    for (int t = 0; t < 8; ++t) sing += ws[WS_SING + t];
    const float recm = r2[0] * (1.f / (float)B_SIZE);
    const float enm  = r1[0] * (1.f / (float)B_SIZE);
    out[0] = recm + 0.1f * enm + 0.005f * sing;
  }
}

extern "C" void kernel_launch(void* const* d_in, const int* in_sizes, int n_in,
                              void* d_out, int out_size, void* d_ws, size_t ws_size,
                              hipStream_t stream) {
  const float* gamma = (const float*)d_in[0];
  const float* feat  = (const float*)d_in[1];
  const float* rec   = (const float*)d_in[2];
  float* ws = (float*)d_ws;
  float* out = (float*)d_out;

  hipLaunchKernelGGL(k_moments, dim3(MOM_BLK), dim3(512), 0, stream,
                     gamma, feat, ws + WS_PART);
  hipLaunchKernelGGL(k_reduce, dim3(34, 8), dim3(256), 0, stream,
                     ws + WS_PART, ws + WS_PART2);
  hipLaunchKernelGGL(k_prepare, dim3(8), dim3(64), 0, stream, ws + WS_PART2, ws);
  hipLaunchKernelGGL(k_energy, dim3(EN_BLK), dim3(256), 0, stream, feat, rec, ws, ws);
  hipLaunchKernelGGL(k_final, dim3(1), dim3(256), 0, stream, ws, out);
}

// Round 10
// 132.363 us; speedup vs baseline: 1.0100x; 1.0100x over previous
//
#include <hip/hip_runtime.h>

using v8h  = __attribute__((ext_vector_type(8))) __fp16;
using h2   = __attribute__((ext_vector_type(2))) __fp16;
using v16f = __attribute__((ext_vector_type(16))) float;
using v4f  = __attribute__((ext_vector_type(4))) float;

#define B_SIZE 262144
// ws float offsets
#define WS_S1    8192    // (inside partial slices) S1[k][d]
#define WS_GS    8448    // (inside partial slices) gsum[k]
#define WS_SING  8456    // 8 : per-k singularity partials
#define WS_C1    8464    // 8 : log(phi)-0.5(logdet+Dlog2pi+|lmu|^2)
#define WS_L16   8736    // 4352 floats = 8704 halfs : M' [272 rows][32] f16
#define WS_ENP   13184   // 1024 energy partials
#define WS_RCP   14208   // 1024 recon partials
#define WS_PART  15360   // 512 x 8464 moment partials (17.3 MB)
#define WS_PART2 4349952 // 8 x 8464 stage-1 reduce partials
#define PART_STRIDE 8464
#define MOM_BLK  512     // 512-thread blocks, 512 rows each
#define EN_BLK   1024    // 256-thread blocks

union PkU { h2 p[4]; v8h v; };

__device__ __forceinline__ float lane_bcast(float v, int l) {
  return __builtin_bit_cast(float,
      __builtin_amdgcn_readlane(__builtin_bit_cast(int, v), l));
}

// ---------------------------------------------------------------------------
// Kernel 1: raw moments, software-pipelined. 8 waves/block, wave w owns k=w.
// Ping-pong LDS staging (no WAR serialization) + one-chunk-ahead register
// prefetch of feat float4s and gamma broadcasts. Barrier-free (wave-private
// staging regions, in-wave lgkmcnt ordering), direct global epilogue.
// 32x32x16 layouts: B[kk][n=c], kk=half*8+j;
// C/D: col=lane&31, row=(reg&3)+8*(reg>>2)+4*(lane>>5).
// ---------------------------------------------------------------------------
__global__ __launch_bounds__(512, 4) void k_moments(
    const float* __restrict__ gamma, const float* __restrict__ feat,
    float* __restrict__ part) {
  __shared__ float stg[8][2][512];             // 32 KB, wave-private ping-pong
  const int tid = threadIdx.x, lane = tid & 63, k = tid >> 6;  // k = wave id
  const int c = lane & 31, half = lane >> 5;
  const int base = blockIdx.x * 512;

  v16f acc;
#pragma unroll
  for (int r = 0; r < 16; ++r) acc[r] = 0.f;
  float s1a = 0.f, ga = 0.f;

  const float4* src = (const float4*)(feat + (size_t)base * 32);
  const float* grow = gamma + (size_t)base * 8 + k;   // gamma col k, row base

  // prologue: prefetch chunk 0
  float4 va = src[lane], vb = src[lane + 64];
  float g8[8];
#pragma unroll
  for (int j = 0; j < 8; ++j) g8[j] = grow[(half * 8 + j) * 8];

  for (int ch = 0; ch < 32; ++ch) {            // 32 chunks of 16 rows
    // prefetch chunk ch+1 (clamped re-read of last chunk at the boundary)
    const int pc = (ch + 1 < 32) ? ch + 1 : 31;
    const float4 na = src[pc * 128 + lane];
    const float4 nb = src[pc * 128 + lane + 64];
    float ng[8];
#pragma unroll
    for (int j = 0; j < 8; ++j) ng[j] = grow[(pc * 16 + half * 8 + j) * 8];

    // stage current chunk into this wave's parity buffer
    float* st = &stg[k][ch & 1][0];
    ((float4*)st)[lane] = va;
    ((float4*)st)[lane + 64] = vb;

    // fragments from LDS (transposed access)
    float fc[8];
#pragma unroll
    for (int j = 0; j < 8; ++j) fc[j] = st[(half * 8 + j) * 32 + c];

    PkU fp, gp;
#pragma unroll
    for (int jj = 0; jj < 4; ++jj) {
      fp.p[jj] = __builtin_amdgcn_cvt_pkrtz(fc[2 * jj], fc[2 * jj + 1]);
      gp.p[jj] = __builtin_amdgcn_cvt_pkrtz(g8[2 * jj], g8[2 * jj + 1]);
    }
#pragma unroll
    for (int j = 0; j < 8; ++j) {
      s1a = fmaf(g8[j], fc[j], s1a);
      ga += g8[j];
    }
    const v8h af = gp.v * fp.v;                // gamma_k ⊙ f
    acc = __builtin_amdgcn_mfma_f32_32x32x16_f16(af, fp.v, acc, 0, 0, 0);

    va = na; vb = nb;
#pragma unroll
    for (int j = 0; j < 8; ++j) g8[j] = ng[j];
  }

  // direct global epilogue (no barrier)
  float* pb = part + (size_t)blockIdx.x * PART_STRIDE;
#pragma unroll
  for (int r = 0; r < 16; ++r) {
    const int row = (r & 3) + 8 * (r >> 2) + 4 * half;
    pb[k * 1024 + row * 32 + c] = acc[r];
  }
  s1a += __shfl_xor(s1a, 32);                  // combine halves
  ga  += __shfl_xor(ga, 32);
  if (half == 0) pb[WS_S1 + k * 32 + c] = s1a;
  if (lane == 0) pb[WS_GS + k] = ga;
}

// ---------------------------------------------------------------------------
// Kernel 1b: stage-1 partial reduction; block (x,y) sums slices [64y,64y+64).
// ---------------------------------------------------------------------------
__global__ void k_reduce(const float* __restrict__ part, float* __restrict__ p2) {
  const int t = blockIdx.x * 256 + threadIdx.x;
  if (t >= 8456) return;
  const int y = blockIdx.y;
  float s = 0.f;
#pragma unroll 8
  for (int b = y * 64; b < y * 64 + 64; ++b)
    s += part[(size_t)b * PART_STRIDE + t];
  p2[(size_t)y * PART_STRIDE + t] = s;
}

// ---------------------------------------------------------------------------
// Kernel 2: one k per block, single wave. Sums the 8 stage-1 slices, then
// in-register Cholesky/solves with readlane broadcasts.
// ---------------------------------------------------------------------------
__global__ __launch_bounds__(64, 1) void k_prepare(
    const float* __restrict__ p2, float* __restrict__ ws) {
  __shared__ float T[32 * 33];
  const int k = blockIdx.x;
  const int i = threadIdx.x & 63;
  const int ri = i & 31;
  const bool act = i < 32;

  float a[32];
#pragma unroll
  for (int j = 0; j < 32; ++j) a[j] = 0.f;
  float s1i = 0.f, gs = 0.f;
#pragma unroll
  for (int y = 0; y < 8; ++y) {
    const float* sl = p2 + (size_t)y * PART_STRIDE;
    const float4* s2p = (const float4*)(sl + k * 1024 + ri * 32);
#pragma unroll
    for (int t = 0; t < 8; ++t) {
      const float4 q = s2p[t];
      a[4 * t + 0] += q.x; a[4 * t + 1] += q.y;
      a[4 * t + 2] += q.z; a[4 * t + 3] += q.w;
    }
    s1i += sl[WS_S1 + k * 32 + ri];
    gs  += sl[WS_GS + k];
  }

  const float denom = gs + 1e-8f;
  const float rden = __builtin_amdgcn_rcpf(denom);
  const float mu_i = s1i * rden;

  float sing = 0.f;
#pragma unroll
  for (int j = 0; j < 32; ++j) {
    const float muj = lane_bcast(mu_i, j);
    const float s1j = lane_bcast(s1i, j);
    float sig = a[j] - mu_i * s1j - muj * s1i + gs * mu_i * muj;
    sig = sig * rden + ((ri == j) ? 1e-6f : 0.f);
    a[j] = sig;
    if (ri == j) sing = __builtin_amdgcn_rcpf(sig + 1e-8f);
  }
  if (!act) sing = 0.f;
#pragma unroll
  for (int m = 1; m < 64; m <<= 1) sing += __shfl_xor(sing, m);
  if (i == 0) ws[WS_SING + k] = sing;

  float logdet = 0.f;
#pragma unroll
  for (int j = 0; j < 32; ++j) {
    const float ajj = lane_bcast(a[j], j);
    const float ljj = __builtin_amdgcn_sqrtf(ajj);
    const float rljj = __builtin_amdgcn_rcpf(ljj);
    logdet += __logf(ajj);
    const float lij = (ri == j) ? ljj : ((ri > j) ? a[j] * rljj : 0.f);
    a[j] = lij;
#pragma unroll
    for (int p = j + 1; p < 32; ++p) {
      const float lpj = lane_bcast(lij, p);
      a[p] = fmaf(-lij, lpj, a[p]);
    }
  }

  const int c = ri;
  float x[32];
#pragma unroll
  for (int r = 0; r < 32; ++r) {
    float s = (r == c) ? 1.f : 0.f;
#pragma unroll
    for (int p = 0; p < r; ++p) {
      const float lrp = lane_bcast(a[p], r);
      s = fmaf(-lrp, x[p], s);
    }
    x[r] = s * __builtin_amdgcn_rcpf(lane_bcast(a[r], r));
  }

  if (act) {
#pragma unroll
    for (int r = 0; r < 32; ++r) T[r * 33 + c] = x[r];
  }
  __syncthreads();
  float xr[32];
#pragma unroll
  for (int p = 0; p < 32; ++p) xr[p] = T[ri * 33 + p];

  __fp16* l16 = (__fp16*)(ws + WS_L16);
  if (act) {
#pragma unroll
    for (int t = 0; t < 4; ++t) {
      PkU h4;
#pragma unroll
      for (int u = 0; u < 4; ++u)
        h4.p[u] = __builtin_amdgcn_cvt_pkrtz(xr[8 * t + 2 * u], xr[8 * t + 2 * u + 1]);
      *(v8h*)(l16 + (size_t)(k * 32 + ri) * 32 + 8 * t) = h4.v;
    }
  }

  float lm = 0.f;
#pragma unroll
  for (int p = 0; p < 32; ++p) lm = fmaf(xr[p], lane_bcast(mu_i, p), lm);

  float lm2 = act ? lm * lm : 0.f;
#pragma unroll
  for (int m = 1; m < 64; m <<= 1) lm2 += __shfl_xor(lm2, m);

  float q = 0.f;
#pragma unroll
  for (int j = 0; j < 32; ++j) q = fmaf(x[j], lane_bcast(lm, j), q);
  if (act) {
    l16[(size_t)(256 + k) * 32 + c] = (__fp16)q;
    l16[(size_t)(264 + k) * 32 + c] = (__fp16)0.f;
  }

  if (i == 0) {
    const float phi = gs * (1.f / (float)B_SIZE);
    ws[WS_C1 + k] =
        __logf(phi + 1e-10f) - 0.5f * (logdet + 32.f * logf(6.28318f)) - 0.5f * lm2;
  }
}

// ---------------------------------------------------------------------------
// Kernel 3: Y = M' F^T via 16x16x32 MFMA; w = c1' + f.q_k - 0.5|y|^2.
// ---------------------------------------------------------------------------
__global__ __launch_bounds__(256, 4) void k_energy(
    const float* __restrict__ feat, const float* __restrict__ rec,
    const float* __restrict__ ws, float* __restrict__ aws) {
  __shared__ float ben[4], brc[4];
  const int tid = threadIdx.x, lane = tid & 63, wv = tid >> 6;
  const int gw = blockIdx.x * 4 + wv;
  const int ROWS = B_SIZE / (EN_BLK * 4);      // 64
  const int base = gw * ROWS;
  const int cl = lane & 15, g = lane >> 4;
  const int p0 = g * 8;

  const __fp16* l16 = (const __fp16*)(ws + WS_L16);
  v8h mf[17];
#pragma unroll
  for (int t = 0; t < 17; ++t)
    mf[t] = *(const v8h*)(l16 + (size_t)(16 * t + cl) * 32 + p0);
  float c1[8];
#pragma unroll
  for (int k = 0; k < 8; ++k) c1[k] = ws[WS_C1 + k];

  float en_acc = 0.f, rv_acc = 0.f;
  const v4f zf = {0.f, 0.f, 0.f, 0.f};

  for (int ch = 0; ch < ROWS / 16; ++ch) {
    const int b0 = base + ch * 16;
    const size_t row = (size_t)(b0 + cl) * 32;
    const float4 fa = *(const float4*)(feat + row + p0);
    const float4 fb = *(const float4*)(feat + row + p0 + 4);
    PkU af;
    af.p[0] = __builtin_amdgcn_cvt_pkrtz(fa.x, fa.y);
    af.p[1] = __builtin_amdgcn_cvt_pkrtz(fa.z, fa.w);
    af.p[2] = __builtin_amdgcn_cvt_pkrtz(fb.x, fb.y);
    af.p[3] = __builtin_amdgcn_cvt_pkrtz(fb.z, fb.w);

    float zk[8];
#pragma unroll
    for (int k = 0; k < 8; ++k) zk[k] = 0.f;
    float yq[4];

#pragma unroll
    for (int t = 0; t < 17; ++t) {
      const v4f y = __builtin_amdgcn_mfma_f32_16x16x32_f16(mf[t], af.v, zf, 0, 0, 0);
      if (t < 16) {
#pragma unroll
        for (int r = 0; r < 4; ++r) zk[t >> 1] = fmaf(y[r], y[r], zk[t >> 1]);
      } else {
#pragma unroll
        for (int r = 0; r < 4; ++r) yq[r] = y[r];
      }
    }
#pragma unroll
    for (int m = 16; m < 64; m <<= 1)
#pragma unroll
      for (int k = 0; k < 8; ++k) zk[k] += __shfl_xor(zk[k], m);

    float mx = -3.0e38f, s = 0.f;
#pragma unroll
    for (int k = 0; k < 8; ++k) {
      const float yp = __shfl(yq[k & 3], cl + ((k >> 2) << 4));
      const float w = c1[k] + yp - 0.5f * zk[k];
      const float mn = fmaxf(mx, w);
      s = s * __expf(mx - mn) + __expf(w - mn);
      mx = mn;
    }
    float en = -(mx + __logf(s + 1e-10f));
    en = (en == en && en < 1e38f && en > -1e38f) ? en : 0.f;
    if (lane < 16) {
      en_acc += en;
      rv_acc += rec[b0 + cl];
    }
  }
#pragma unroll
  for (int m = 32; m; m >>= 1) {
    en_acc += __shfl_down(en_acc, m);
    rv_acc += __shfl_down(rv_acc, m);
  }
  if (lane == 0) { ben[wv] = en_acc; brc[wv] = rv_acc; }
  __syncthreads();
  if (tid == 0) {
    aws[WS_ENP + blockIdx.x] = ben[0] + ben[1] + ben[2] + ben[3];
    aws[WS_RCP + blockIdx.x] = brc[0] + brc[1] + brc[2] + brc[3];
  }
}

// ---------------------------------------------------------------------------
// Kernel 4: final reduction + combine.
// ---------------------------------------------------------------------------
__global__ void k_final(const float* __restrict__ ws, float* __restrict__ out) {
  __shared__ float r1[256], r2[256];
  const int tid = threadIdx.x;
  float e = 0.f, r = 0.f;
  for (int i = tid; i < EN_BLK; i += 256) {
    e += ws[WS_ENP + i];
    r += ws[WS_RCP + i];
  }
  r1[tid] = e; r2[tid] = r;
  __syncthreads();
  for (int s = 128; s > 0; s >>= 1) {
    if (tid < s) { r1[tid] += r1[tid + s]; r2[tid] += r2[tid + s]; }
    __syncthreads();
  }
  if (tid == 0) {
    float sing = 0.f;
    for (int t = 0; t < 8; ++t) sing += ws[WS_SING + t];
    const float recm = r2[0] * (1.f / (float)B_SIZE);
    const float enm  = r1[0] * (1.f / (float)B_SIZE);
    out[0] = recm + 0.1f * enm + 0.005f * sing;
  }
}

extern "C" void kernel_launch(void* const* d_in, const int* in_sizes, int n_in,
                              void* d_out, int out_size, void* d_ws, size_t ws_size,
                              hipStream_t stream) {
  const float* gamma = (const float*)d_in[0];
  const float* feat  = (const float*)d_in[1];
  const float* rec   = (const float*)d_in[2];
  float* ws = (float*)d_ws;
  float* out = (float*)d_out;

  hipLaunchKernelGGL(k_moments, dim3(MOM_BLK), dim3(512), 0, stream,
                     gamma, feat, ws + WS_PART);
  hipLaunchKernelGGL(k_reduce, dim3(34, 8), dim3(256), 0, stream,
                     ws + WS_PART, ws + WS_PART2);
  hipLaunchKernelGGL(k_prepare, dim3(8), dim3(64), 0, stream, ws + WS_PART2, ws);
  hipLaunchKernelGGL(k_energy, dim3(EN_BLK), dim3(256), 0, stream, feat, rec, ws, ws);
  hipLaunchKernelGGL(k_final, dim3(1), dim3(256), 0, stream, ws, out);
}